// Round 6
// baseline (477.902 us; speedup 1.0000x reference)
//
#include <hip/hip_runtime.h>
#include <hip/hip_bf16.h>

#define NEGV (-10000.0f)
constexpr int B_ = 32, S_ = 256, D_ = 512, K_ = 8, L_ = 64;

typedef __bf16 bf16_t;
typedef bf16_t bf16x8 __attribute__((ext_vector_type(8)));
typedef float f32x4 __attribute__((ext_vector_type(4)));

// ---------------------------------------------------------------------------
// cast word_rep (fp32, 32*256*512) -> bf16 A matrix [8192][512]
// ---------------------------------------------------------------------------
__global__ __launch_bounds__(256) void cast_kernel(const float* __restrict__ wr,
                                                   bf16_t* __restrict__ Awr) {
  const int i = (blockIdx.x * 256 + threadIdx.x) * 8;
  const float4 a = *(const float4*)(wr + i);
  const float4 b = *(const float4*)(wr + i + 4);
  bf16x8 o;
  o[0] = (bf16_t)a.x; o[1] = (bf16_t)a.y; o[2] = (bf16_t)a.z; o[3] = (bf16_t)a.w;
  o[4] = (bf16_t)b.x; o[5] = (bf16_t)b.y; o[6] = (bf16_t)b.z; o[7] = (bf16_t)b.w;
  *(bf16x8*)(Awr + i) = o;
}

// ---------------------------------------------------------------------------
// Vt[(k*64+l)][(o*512+i)] = (k>=o) ? sum_d conv_w[k][d][i][k-o] * cls_w[l][d] : 0
// bf16, B^T layout [512][4096]. grid (8 i-tiles, 8 h, 8 k).
// ---------------------------------------------------------------------------
__global__ __launch_bounds__(256) void w2_kernel(const float* __restrict__ conv_w,
                                                 const float* __restrict__ cls_w,
                                                 bf16_t* __restrict__ Vt) {
  const int h = blockIdx.y, k = blockIdx.z;
  const int i0 = blockIdx.x * 64;
  const int tid = threadIdx.x;
  if (h > k) {  // zero-fill region o=h (>k)
    uint4 z; z.x = z.y = z.z = z.w = 0u;
#pragma unroll
    for (int q = 0; q < 2; q++) {
      const int c = tid + q * 256;
      const int l = c >> 3, cc = c & 7;
      *(uint4*)(Vt + (size_t)(k * 64 + l) * 4096 + h * 512 + i0 + cc * 8) = z;
    }
    return;
  }
  __shared__ __align__(16) float As[32 * 64];
  __shared__ __align__(16) float Bs[32 * 65];
  __shared__ __align__(16) bf16_t Ls2[64 * 72];
  float acc[16];
#pragma unroll
  for (int q = 0; q < 16; q++) acc[q] = 0.f;
  const int tr = tid >> 4, tc = tid & 15;
  for (int d0 = 0; d0 < D_; d0 += 32) {
#pragma unroll
    for (int q = 0; q < 8; q++) {
      const int dd = tid >> 3;
      const int ii = (tid & 7) * 8 + q;
      As[dd * 64 + ii] = conv_w[(size_t)((k * D_ + d0 + dd) * D_ + i0 + ii) * 8 + h];
      const int ll = tid >> 2;
      const int d2 = (tid & 3) * 8 + q;
      Bs[d2 * 65 + ll] = cls_w[ll * D_ + d0 + d2];
    }
    __syncthreads();
#pragma unroll 4
    for (int kk = 0; kk < 32; kk++) {
      float a[4], bb[4];
#pragma unroll
      for (int r = 0; r < 4; r++) a[r] = As[kk * 64 + tr * 4 + r];
#pragma unroll
      for (int c = 0; c < 4; c++) bb[c] = Bs[kk * 65 + tc * 4 + c];
#pragma unroll
      for (int r = 0; r < 4; r++)
#pragma unroll
        for (int c = 0; c < 4; c++) acc[r * 4 + c] += a[r] * bb[c];
    }
    __syncthreads();
  }
#pragma unroll
  for (int r = 0; r < 4; r++)
#pragma unroll
    for (int c = 0; c < 4; c++)
      Ls2[(tc * 4 + c) * 72 + tr * 4 + r] = (bf16_t)acc[r * 4 + c];
  __syncthreads();
  const int o = k - h;
#pragma unroll
  for (int q = 0; q < 2; q++) {
    const int c = tid + q * 256;
    const int l = c >> 3, cc = c & 7;
    const uint4 v = *(const uint4*)(&Ls2[l * 72 + cc * 8]);
    *(uint4*)(Vt + (size_t)(k * 64 + l) * 4096 + o * 512 + i0 + cc * 8) = v;
  }
}

// ---------------------------------------------------------------------------
// bias2[k][l] = cls_b[l] + sum_d conv_b[k][d] * cls_w[l][d]
// ---------------------------------------------------------------------------
__global__ void bias2_kernel(const float* __restrict__ conv_b, const float* __restrict__ cls_w,
                             const float* __restrict__ cls_b, float* __restrict__ bias2) {
  const int idx = blockIdx.x * 256 + threadIdx.x;
  const int k = idx >> 6, l = idx & 63;
  float s = cls_b[l];
  for (int d = 0; d < D_; d++) s += conv_b[k * D_ + d] * cls_w[l * D_ + d];
  bias2[idx] = s;
}

// ---------------------------------------------------------------------------
// MFMA GEMM -> ELS = exp(label_score), layout [m=8192][l*8+k].
// Strip-pair blocks (kHi=7-p, kLo=p): 144 kt-iters uniform over 256 blocks.
// ---------------------------------------------------------------------------
__global__ __launch_bounds__(256) void ls_mfma(const bf16_t* __restrict__ Awr,
                                               const bf16_t* __restrict__ Vt,
                                               const float* __restrict__ bias2,
                                               const int* __restrict__ mask,
                                               float* __restrict__ ELS) {
  constexpr int LDA = 40;
  __shared__ __align__(16) bf16_t As[128 * LDA];
  __shared__ __align__(16) bf16_t Bs[64 * LDA];
  const int tid = threadIdx.x;
  const int m0 = blockIdx.x * 128;
  const int p = blockIdx.y;
  const int w = tid >> 6, lane = tid & 63;
  const int wm = w & 1, wn = w >> 1;
  const int lrow = lane & 15, quad = lane >> 4;
  for (int s = 0; s < 2; s++) {
    const int kS = (s == 0) ? (7 - p) : p;
    const int KT = (kS + 1) * 16;
    f32x4 acc[4][2] = {};
    for (int kt = 0; kt < KT; kt++) {
      const int j0 = kt * 32;
      const int o = j0 >> 9;
      // A tile: 128 rows x 32 cols = 512 chunks of 8 bf16
#pragma unroll
      for (int q = 0; q < 2; q++) {
        const int c = tid + q * 256;
        const int row = c >> 2, cc = c & 3;
        int src = m0 + row - o;
        if (src < 0) src = 0;  // garbage feeds only t<k-masked outputs
        const uint4 va = *(const uint4*)(Awr + (size_t)src * 512 + (j0 & 511) + cc * 8);
        *(uint4*)(&As[row * LDA + cc * 8]) = va;
      }
      // B tile: 64 rows x 32 cols = 256 chunks of 8 bf16
      {
        const int br = tid >> 2, bc = tid & 3;
        const uint4 vb = *(const uint4*)(Vt + (size_t)(kS * 64 + br) * 4096 + j0 + bc * 8);
        *(uint4*)(&Bs[br * LDA + bc * 8]) = vb;
      }
      __syncthreads();
      bf16x8 af[4], bfr[2];
#pragma unroll
      for (int mi = 0; mi < 4; mi++)
        af[mi] = *(const bf16x8*)(&As[(wm * 64 + mi * 16 + lrow) * LDA + quad * 8]);
#pragma unroll
      for (int ni = 0; ni < 2; ni++)
        bfr[ni] = *(const bf16x8*)(&Bs[(wn * 32 + ni * 16 + lrow) * LDA + quad * 8]);
#pragma unroll
      for (int mi = 0; mi < 4; mi++)
#pragma unroll
        for (int ni = 0; ni < 2; ni++)
          acc[mi][ni] = __builtin_amdgcn_mfma_f32_16x16x32_bf16(af[mi], bfr[ni], acc[mi][ni], 0, 0, 0);
      __syncthreads();
    }
    // epilogue for strip kS
    float bn[2];
    int lcol[2];
#pragma unroll
    for (int ni = 0; ni < 2; ni++) {
      lcol[ni] = wn * 32 + ni * 16 + lrow;
      bn[ni] = bias2[kS * 64 + lcol[ni]];
    }
#pragma unroll
    for (int mi = 0; mi < 4; mi++) {
#pragma unroll
      for (int d = 0; d < 4; d++) {
        const int m = m0 + wm * 64 + mi * 16 + quad * 4 + d;
        const int t = m & 255;
        const bool mok = (mask[m] == 1);
#pragma unroll
        for (int ni = 0; ni < 2; ni++) {
          const float v = acc[mi][ni][d] + bn[ni];
          const float e = (!mok || t < kS || lcol[ni] == 0) ? 0.f : __expf(v);
          ELS[(size_t)m * 512 + lcol[ni] * 8 + kS] = e;
        }
      }
    }
  }
}

// ---------------------------------------------------------------------------
// Linear-domain semi-CRF DP. One wave per b; lane = label l.
// __launch_bounds__(64,1): allow up to 512 VGPRs so rT[16] (64 regs) and the
// 16 in-flight LDS read results all stay resident -> reads pipeline.
// ---------------------------------------------------------------------------
__global__ __launch_bounds__(64, 1) void dp_kernel(const float* __restrict__ T,
                                                   const float* __restrict__ Tfb_g,
                                                   const float* __restrict__ ELS,
                                                   float* __restrict__ Mg_lin,
                                                   float* __restrict__ cs_g) {
  const int b = blockIdx.x, l = threadIdx.x;
  f32x4 rT[16];
#pragma unroll
  for (int j = 0; j < 16; j++) {
    f32x4 r;
#pragma unroll
    for (int q = 0; q < 4; q++) r[q] = __expf(T[l * 64 + j * 4 + q]);
    rT[j] = r;
  }
  __shared__ __align__(16) float eb[2][64];
  float mh[8];
  mh[0] = __expf(Tfb_g[l]);  // BEGIN phantom
#pragma unroll
  for (int u = 1; u < 8; u++) mh[u] = 0.f;
  float c = 0.f;
  const float* ep = ELS + (size_t)b * 256 * 512 + l * 8;
  float4 p0a = *(const float4*)(ep);
  float4 p0b = *(const float4*)(ep + 4);
  float4 p1a = *(const float4*)(ep + 512);
  float4 p1b = *(const float4*)(ep + 516);
  for (int t = 0; t < 256; t++) {
    const float4 ca = p0a, cb = p0b;
    p0a = p1a; p0b = p1b;
    if (t + 2 < 256) {
      p1a = *(const float4*)(ep + (size_t)(t + 2) * 512);
      p1b = *(const float4*)(ep + (size_t)(t + 2) * 512 + 4);
    }
    // e = sum_k els[k] * mh[k]
    float e0 = ca.x * mh[0] + ca.y * mh[1];
    float e1 = ca.z * mh[2] + ca.w * mh[3];
    float e2 = cb.x * mh[4] + cb.y * mh[5];
    float e3 = cb.z * mh[6] + cb.w * mh[7];
    const float e = (e0 + e1) + (e2 + e3);
    eb[t & 1][l] = e;
    // 16 independent b128 loads, all issued before any use
    const f32x4* evp = (const f32x4*)(&eb[t & 1][0]);
    const f32x4 v0 = evp[0],  v1 = evp[1],  v2 = evp[2],  v3 = evp[3];
    const f32x4 v4 = evp[4],  v5 = evp[5],  v6 = evp[6],  v7 = evp[7];
    const f32x4 v8 = evp[8],  v9 = evp[9],  v10 = evp[10], v11 = evp[11];
    const f32x4 v12 = evp[12], v13 = evp[13], v14 = evp[14], v15 = evp[15];
    f32x4 a0 = rT[0] * v0,  a1 = rT[1] * v1,  a2 = rT[2] * v2,  a3 = rT[3] * v3;
    f32x4 a4 = rT[4] * v4,  a5 = rT[5] * v5,  a6 = rT[6] * v6,  a7 = rT[7] * v7;
    a0 += rT[8] * v8;   a1 += rT[9] * v9;   a2 += rT[10] * v10; a3 += rT[11] * v11;
    a4 += rT[12] * v12; a5 += rT[13] * v13; a6 += rT[14] * v14; a7 += rT[15] * v15;
    f32x4 mx0 = __builtin_elementwise_max(v0, v1);
    f32x4 mx1 = __builtin_elementwise_max(v2, v3);
    f32x4 mx2 = __builtin_elementwise_max(v4, v5);
    f32x4 mx3 = __builtin_elementwise_max(v6, v7);
    mx0 = __builtin_elementwise_max(mx0, __builtin_elementwise_max(v8, v9));
    mx1 = __builtin_elementwise_max(mx1, __builtin_elementwise_max(v10, v11));
    mx2 = __builtin_elementwise_max(mx2, __builtin_elementwise_max(v12, v13));
    mx3 = __builtin_elementwise_max(mx3, __builtin_elementwise_max(v14, v15));
    const f32x4 as = ((a0 + a1) + (a2 + a3)) + ((a4 + a5) + (a6 + a7));
    const float m4 = (as[0] + as[1]) + (as[2] + as[3]);
    const f32x4 mxv = __builtin_elementwise_max(__builtin_elementwise_max(mx0, mx1),
                                                __builtin_elementwise_max(mx2, mx3));
    float S = fmaxf(fmaxf(mxv[0], mxv[1]), fmaxf(mxv[2], mxv[3]));
    Mg_lin[((size_t)b * 256 + t) * 64 + l] = m4;
    if (l == 0) cs_g[b * 256 + t] = c;
    S = fmaxf(S, 1e-30f);
    const float inv = __builtin_amdgcn_rcpf(S);
    c += __logf(S);
#pragma unroll
    for (int u = 7; u >= 1; u--) mh[u] = mh[u - 1] * inv;
    mh[0] = m4 * inv;
  }
}

// ---------------------------------------------------------------------------
// Final gather (one wave per b): out[b] = LSE_{k,l}(row_{len-1-k}[k,l] + T2e[l])
// ---------------------------------------------------------------------------
__global__ __launch_bounds__(64) void final_kernel(const int* __restrict__ mask,
                                                   const float* __restrict__ Tfb_g,
                                                   const float* __restrict__ T2e_g,
                                                   const float* __restrict__ ELS,
                                                   const float* __restrict__ Mg_lin,
                                                   const float* __restrict__ cs_g,
                                                   float* __restrict__ out) {
  const int b = blockIdx.x, lane = threadIdx.x;
  int lenp = 0;
  for (int s = lane; s < S_; s += 64) lenp += (mask[b * S_ + s] == 1) ? 1 : 0;
#pragma unroll
  for (int off = 32; off > 0; off >>= 1) lenp += __shfl_xor(lenp, off);
  const int len = lenp;
  const float t2e = T2e_g[lane];
  float vals[8];
  float mx = -3.4e38f;
#pragma unroll
  for (int k = 0; k < 8; k++) {
    int tk = len - 1 - k;
    if (tk < 0) tk = S_ - 1;
    float g;
    if (k > tk) {
      g = NEGV;
    } else {
      const float elsv = ELS[((size_t)(b * S_ + tk)) * 512 + lane * 8 + k];
      const float ls = (elsv > 0.f) ? __logf(elsv) : NEGV;
      if (k == tk) {
        g = ls + Tfb_g[lane];
      } else if (mask[b * S_ + tk] == 1) {
        const int u = tk - 1 - k;
        const float mlin = Mg_lin[((size_t)b * S_ + u) * 64 + lane];
        const float M = (mlin > 0.f) ? (__logf(mlin) + cs_g[b * S_ + u]) : -1e30f;
        g = ls + M;
      } else {
        g = NEGV;
      }
    }
    const float v = g + t2e;
    vals[k] = v;
    mx = fmaxf(mx, v);
  }
#pragma unroll
  for (int off = 32; off > 0; off >>= 1) mx = fmaxf(mx, __shfl_xor(mx, off));
  float s = 0.f;
#pragma unroll
  for (int k = 0; k < 8; k++) s += __expf(vals[k] - mx);
#pragma unroll
  for (int off = 32; off > 0; off >>= 1) s += __shfl_xor(s, off);
  if (lane == 0) out[b] = __logf(s) + mx;
}

// ---------------------------------------------------------------------------
extern "C" void kernel_launch(void* const* d_in, const int* in_sizes, int n_in,
                              void* d_out, int out_size, void* d_ws, size_t ws_size,
                              hipStream_t stream) {
  const float* wr     = (const float*)d_in[0];
  const int*   mask   = (const int*)d_in[1];
  const float* conv_w = (const float*)d_in[2];
  const float* conv_b = (const float*)d_in[3];
  const float* cls_w  = (const float*)d_in[4];
  const float* cls_b  = (const float*)d_in[5];
  const float* T      = (const float*)d_in[6];
  const float* Tfb    = (const float*)d_in[7];
  const float* T2e    = (const float*)d_in[8];
  float* out = (float*)d_out;

  float* ws = (float*)d_ws;
  bf16_t* Vt    = (bf16_t*)ws;              // [512][4096] bf16  (1,048,576 f)
  bf16_t* Awr   = (bf16_t*)(ws + 1048576);  // [8192][512] bf16  (2,097,152 f)
  float*  bias2 = ws + 3145728;             // [8][64]
  float*  ELS   = ws + 3146240;             // [8192][512] fp32  (4,194,304 f)
  float*  Mg    = ws + 7340544;             // [32][256][64]     (524,288 f)
  float*  cs    = ws + 7864832;             // [32][256]         (8,192 f)
  // total 7,873,024 floats = 31.5 MB

  cast_kernel<<<2048, 256, 0, stream>>>(wr, Awr);
  w2_kernel<<<dim3(8, 8, 8), 256, 0, stream>>>(conv_w, cls_w, Vt);
  bias2_kernel<<<2, 256, 0, stream>>>(conv_b, cls_w, cls_b, bias2);
  ls_mfma<<<dim3(64, 4), 256, 0, stream>>>(Awr, Vt, bias2, mask, ELS);
  dp_kernel<<<32, 64, 0, stream>>>(T, Tfb, ELS, Mg, cs);
  final_kernel<<<32, 64, 0, stream>>>(mask, Tfb, T2e, ELS, Mg, cs, out);
}

// Round 7
// 400.631 us; speedup vs baseline: 1.1929x; 1.1929x over previous
//
#include <hip/hip_runtime.h>
#include <hip/hip_bf16.h>

#define NEGV (-10000.0f)
constexpr int B_ = 32, S_ = 256, D_ = 512, K_ = 8, L_ = 64;

typedef __bf16 bf16_t;
typedef bf16_t bf16x8 __attribute__((ext_vector_type(8)));
typedef float f32x4 __attribute__((ext_vector_type(4)));

__device__ __forceinline__ float u2f(unsigned int u) {
  union { unsigned int u; float f; } x; x.u = u; return x.f;
}

// ---------------------------------------------------------------------------
// cast word_rep (fp32, 32*256*512) -> bf16 A matrix [8192][512]
// ---------------------------------------------------------------------------
__global__ __launch_bounds__(256) void cast_kernel(const float* __restrict__ wr,
                                                   bf16_t* __restrict__ Awr) {
  const int i = (blockIdx.x * 256 + threadIdx.x) * 8;
  const float4 a = *(const float4*)(wr + i);
  const float4 b = *(const float4*)(wr + i + 4);
  bf16x8 o;
  o[0] = (bf16_t)a.x; o[1] = (bf16_t)a.y; o[2] = (bf16_t)a.z; o[3] = (bf16_t)a.w;
  o[4] = (bf16_t)b.x; o[5] = (bf16_t)b.y; o[6] = (bf16_t)b.z; o[7] = (bf16_t)b.w;
  *(bf16x8*)(Awr + i) = o;
}

// ---------------------------------------------------------------------------
// Vt[(k*64+l)][(o*512+i)] = (k>=o) ? sum_d conv_w[k][d][i][k-o] * cls_w[l][d] : 0
// ---------------------------------------------------------------------------
__global__ __launch_bounds__(256) void w2_kernel(const float* __restrict__ conv_w,
                                                 const float* __restrict__ cls_w,
                                                 bf16_t* __restrict__ Vt) {
  const int h = blockIdx.y, k = blockIdx.z;
  const int i0 = blockIdx.x * 64;
  const int tid = threadIdx.x;
  if (h > k) {  // zero-fill region o=h (>k)
    uint4 z; z.x = z.y = z.z = z.w = 0u;
#pragma unroll
    for (int q = 0; q < 2; q++) {
      const int c = tid + q * 256;
      const int l = c >> 3, cc = c & 7;
      *(uint4*)(Vt + (size_t)(k * 64 + l) * 4096 + h * 512 + i0 + cc * 8) = z;
    }
    return;
  }
  __shared__ __align__(16) float As[32 * 64];
  __shared__ __align__(16) float Bs[32 * 65];
  __shared__ __align__(16) bf16_t Ls2[64 * 72];
  float acc[16];
#pragma unroll
  for (int q = 0; q < 16; q++) acc[q] = 0.f;
  const int tr = tid >> 4, tc = tid & 15;
  for (int d0 = 0; d0 < D_; d0 += 32) {
#pragma unroll
    for (int q = 0; q < 8; q++) {
      const int dd = tid >> 3;
      const int ii = (tid & 7) * 8 + q;
      As[dd * 64 + ii] = conv_w[(size_t)((k * D_ + d0 + dd) * D_ + i0 + ii) * 8 + h];
      const int ll = tid >> 2;
      const int d2 = (tid & 3) * 8 + q;
      Bs[d2 * 65 + ll] = cls_w[ll * D_ + d0 + d2];
    }
    __syncthreads();
#pragma unroll 4
    for (int kk = 0; kk < 32; kk++) {
      float a[4], bb[4];
#pragma unroll
      for (int r = 0; r < 4; r++) a[r] = As[kk * 64 + tr * 4 + r];
#pragma unroll
      for (int c = 0; c < 4; c++) bb[c] = Bs[kk * 65 + tc * 4 + c];
#pragma unroll
      for (int r = 0; r < 4; r++)
#pragma unroll
        for (int c = 0; c < 4; c++) acc[r * 4 + c] += a[r] * bb[c];
    }
    __syncthreads();
  }
#pragma unroll
  for (int r = 0; r < 4; r++)
#pragma unroll
    for (int c = 0; c < 4; c++)
      Ls2[(tc * 4 + c) * 72 + tr * 4 + r] = (bf16_t)acc[r * 4 + c];
  __syncthreads();
  const int o = k - h;
#pragma unroll
  for (int q = 0; q < 2; q++) {
    const int c = tid + q * 256;
    const int l = c >> 3, cc = c & 7;
    const uint4 v = *(const uint4*)(&Ls2[l * 72 + cc * 8]);
    *(uint4*)(Vt + (size_t)(k * 64 + l) * 4096 + o * 512 + i0 + cc * 8) = v;
  }
}

// ---------------------------------------------------------------------------
// bias2[k][l] = cls_b[l] + sum_d conv_b[k][d] * cls_w[l][d]
// ---------------------------------------------------------------------------
__global__ void bias2_kernel(const float* __restrict__ conv_b, const float* __restrict__ cls_w,
                             const float* __restrict__ cls_b, float* __restrict__ bias2) {
  const int idx = blockIdx.x * 256 + threadIdx.x;
  const int k = idx >> 6, l = idx & 63;
  float s = cls_b[l];
  for (int d = 0; d < D_; d++) s += conv_b[k * D_ + d] * cls_w[l * D_ + d];
  bias2[idx] = s;
}

// ---------------------------------------------------------------------------
// MFMA GEMM -> ELSb = exp(label_score) as bf16, layout [m=8192][l*8+k].
// ---------------------------------------------------------------------------
__global__ __launch_bounds__(256) void ls_mfma(const bf16_t* __restrict__ Awr,
                                               const bf16_t* __restrict__ Vt,
                                               const float* __restrict__ bias2,
                                               const int* __restrict__ mask,
                                               bf16_t* __restrict__ ELSb) {
  constexpr int LDA = 40;
  __shared__ __align__(16) bf16_t As[128 * LDA];
  __shared__ __align__(16) bf16_t Bs[64 * LDA];
  const int tid = threadIdx.x;
  const int m0 = blockIdx.x * 128;
  const int p = blockIdx.y;
  const int w = tid >> 6, lane = tid & 63;
  const int wm = w & 1, wn = w >> 1;
  const int lrow = lane & 15, quad = lane >> 4;
  for (int s = 0; s < 2; s++) {
    const int kS = (s == 0) ? (7 - p) : p;
    const int KT = (kS + 1) * 16;
    f32x4 acc[4][2] = {};
    for (int kt = 0; kt < KT; kt++) {
      const int j0 = kt * 32;
      const int o = j0 >> 9;
#pragma unroll
      for (int q = 0; q < 2; q++) {
        const int c = tid + q * 256;
        const int row = c >> 2, cc = c & 3;
        int src = m0 + row - o;
        if (src < 0) src = 0;  // garbage feeds only t<k-masked outputs
        const uint4 va = *(const uint4*)(Awr + (size_t)src * 512 + (j0 & 511) + cc * 8);
        *(uint4*)(&As[row * LDA + cc * 8]) = va;
      }
      {
        const int br = tid >> 2, bc = tid & 3;
        const uint4 vb = *(const uint4*)(Vt + (size_t)(kS * 64 + br) * 4096 + j0 + bc * 8);
        *(uint4*)(&Bs[br * LDA + bc * 8]) = vb;
      }
      __syncthreads();
      bf16x8 af[4], bfr[2];
#pragma unroll
      for (int mi = 0; mi < 4; mi++)
        af[mi] = *(const bf16x8*)(&As[(wm * 64 + mi * 16 + lrow) * LDA + quad * 8]);
#pragma unroll
      for (int ni = 0; ni < 2; ni++)
        bfr[ni] = *(const bf16x8*)(&Bs[(wn * 32 + ni * 16 + lrow) * LDA + quad * 8]);
#pragma unroll
      for (int mi = 0; mi < 4; mi++)
#pragma unroll
        for (int ni = 0; ni < 2; ni++)
          acc[mi][ni] = __builtin_amdgcn_mfma_f32_16x16x32_bf16(af[mi], bfr[ni], acc[mi][ni], 0, 0, 0);
      __syncthreads();
    }
    // epilogue for strip kS -> bf16 exp values
    float bn[2];
    int lcol[2];
#pragma unroll
    for (int ni = 0; ni < 2; ni++) {
      lcol[ni] = wn * 32 + ni * 16 + lrow;
      bn[ni] = bias2[kS * 64 + lcol[ni]];
    }
#pragma unroll
    for (int mi = 0; mi < 4; mi++) {
#pragma unroll
      for (int d = 0; d < 4; d++) {
        const int m = m0 + wm * 64 + mi * 16 + quad * 4 + d;
        const int t = m & 255;
        const bool mok = (mask[m] == 1);
#pragma unroll
        for (int ni = 0; ni < 2; ni++) {
          const float v = acc[mi][ni][d] + bn[ni];
          const float e = (!mok || t < kS || lcol[ni] == 0) ? 0.f : __expf(v);
          ELSb[(size_t)m * 512 + lcol[ni] * 8 + kS] = (bf16_t)e;
        }
      }
    }
  }
}

// ---------------------------------------------------------------------------
// Linear-domain semi-CRF DP. One wave per b; lane = label l.
// ELS in bf16: one dwordx4 per lane per step, register ring prefetch depth 4
// (covers HBM latency). Matvec via broadcast LDS reads as before.
// ---------------------------------------------------------------------------
__global__ __launch_bounds__(64, 1) void dp_kernel(const float* __restrict__ T,
                                                   const float* __restrict__ Tfb_g,
                                                   const bf16_t* __restrict__ ELSb,
                                                   float* __restrict__ Mg_lin,
                                                   float* __restrict__ cs_g) {
  const int b = blockIdx.x, l = threadIdx.x;
  f32x4 rT[16];
#pragma unroll
  for (int j = 0; j < 16; j++) {
    f32x4 r;
#pragma unroll
    for (int q = 0; q < 4; q++) r[q] = __expf(T[l * 64 + j * 4 + q]);
    rT[j] = r;
  }
  __shared__ __align__(16) float eb[2][64];
  float mh0 = __expf(Tfb_g[l]);  // BEGIN phantom
  float mh1 = 0.f, mh2 = 0.f, mh3 = 0.f, mh4 = 0.f, mh5 = 0.f, mh6 = 0.f, mh7 = 0.f;
  float c = 0.f;
  const bf16_t* ep = ELSb + (size_t)b * 256 * 512 + l * 8;
  uint4 r0 = *(const uint4*)(ep + 0 * 512);
  uint4 r1 = *(const uint4*)(ep + 1 * 512);
  uint4 r2 = *(const uint4*)(ep + 2 * 512);
  uint4 r3 = *(const uint4*)(ep + 3 * 512);

  auto step = [&](const uint4 q, const int t) {
    const float f0 = u2f(q.x << 16), f1 = u2f(q.x & 0xFFFF0000u);
    const float f2 = u2f(q.y << 16), f3 = u2f(q.y & 0xFFFF0000u);
    const float f4 = u2f(q.z << 16), f5 = u2f(q.z & 0xFFFF0000u);
    const float f6 = u2f(q.w << 16), f7 = u2f(q.w & 0xFFFF0000u);
    const float e = ((f0 * mh0 + f1 * mh1) + (f2 * mh2 + f3 * mh3)) +
                    ((f4 * mh4 + f5 * mh5) + (f6 * mh6 + f7 * mh7));
    eb[t & 1][l] = e;
    const f32x4* evp = (const f32x4*)(&eb[t & 1][0]);
    const f32x4 v0 = evp[0],  v1 = evp[1],  v2 = evp[2],  v3 = evp[3];
    const f32x4 v4 = evp[4],  v5 = evp[5],  v6 = evp[6],  v7 = evp[7];
    const f32x4 v8 = evp[8],  v9 = evp[9],  v10 = evp[10], v11 = evp[11];
    const f32x4 v12 = evp[12], v13 = evp[13], v14 = evp[14], v15 = evp[15];
    f32x4 a0 = rT[0] * v0,  a1 = rT[1] * v1,  a2 = rT[2] * v2,  a3 = rT[3] * v3;
    f32x4 a4 = rT[4] * v4,  a5 = rT[5] * v5,  a6 = rT[6] * v6,  a7 = rT[7] * v7;
    a0 += rT[8] * v8;   a1 += rT[9] * v9;   a2 += rT[10] * v10; a3 += rT[11] * v11;
    a4 += rT[12] * v12; a5 += rT[13] * v13; a6 += rT[14] * v14; a7 += rT[15] * v15;
    f32x4 mx0 = __builtin_elementwise_max(v0, v1);
    f32x4 mx1 = __builtin_elementwise_max(v2, v3);
    f32x4 mx2 = __builtin_elementwise_max(v4, v5);
    f32x4 mx3 = __builtin_elementwise_max(v6, v7);
    mx0 = __builtin_elementwise_max(mx0, __builtin_elementwise_max(v8, v9));
    mx1 = __builtin_elementwise_max(mx1, __builtin_elementwise_max(v10, v11));
    mx2 = __builtin_elementwise_max(mx2, __builtin_elementwise_max(v12, v13));
    mx3 = __builtin_elementwise_max(mx3, __builtin_elementwise_max(v14, v15));
    const f32x4 as = ((a0 + a1) + (a2 + a3)) + ((a4 + a5) + (a6 + a7));
    const float m4 = (as[0] + as[1]) + (as[2] + as[3]);
    const f32x4 mxv = __builtin_elementwise_max(__builtin_elementwise_max(mx0, mx1),
                                                __builtin_elementwise_max(mx2, mx3));
    float S = fmaxf(fmaxf(mxv[0], mxv[1]), fmaxf(mxv[2], mxv[3]));
    Mg_lin[((size_t)b * 256 + t) * 64 + l] = m4;
    if (l == 0) cs_g[b * 256 + t] = c;
    S = fmaxf(S, 1e-30f);
    const float inv = __builtin_amdgcn_rcpf(S);
    c += __logf(S);
    mh7 = mh6 * inv; mh6 = mh5 * inv; mh5 = mh4 * inv; mh4 = mh3 * inv;
    mh3 = mh2 * inv; mh2 = mh1 * inv; mh1 = mh0 * inv; mh0 = m4 * inv;
  };

  for (int t = 0; t < 256; t += 4) {
    step(r0, t + 0);
    { const int u = (t + 4 < 256) ? t + 4 : 255; r0 = *(const uint4*)(ep + (size_t)u * 512); }
    step(r1, t + 1);
    { const int u = (t + 5 < 256) ? t + 5 : 255; r1 = *(const uint4*)(ep + (size_t)u * 512); }
    step(r2, t + 2);
    { const int u = (t + 6 < 256) ? t + 6 : 255; r2 = *(const uint4*)(ep + (size_t)u * 512); }
    step(r3, t + 3);
    { const int u = (t + 7 < 256) ? t + 7 : 255; r3 = *(const uint4*)(ep + (size_t)u * 512); }
  }
}

// ---------------------------------------------------------------------------
// Final gather (one wave per b): out[b] = LSE_{k,l}(row_{len-1-k}[k,l] + T2e[l])
// ---------------------------------------------------------------------------
__global__ __launch_bounds__(64) void final_kernel(const int* __restrict__ mask,
                                                   const float* __restrict__ Tfb_g,
                                                   const float* __restrict__ T2e_g,
                                                   const bf16_t* __restrict__ ELSb,
                                                   const float* __restrict__ Mg_lin,
                                                   const float* __restrict__ cs_g,
                                                   float* __restrict__ out) {
  const int b = blockIdx.x, lane = threadIdx.x;
  int lenp = 0;
  for (int s = lane; s < S_; s += 64) lenp += (mask[b * S_ + s] == 1) ? 1 : 0;
#pragma unroll
  for (int off = 32; off > 0; off >>= 1) lenp += __shfl_xor(lenp, off);
  const int len = lenp;
  const float t2e = T2e_g[lane];
  float vals[8];
  float mx = -3.4e38f;
#pragma unroll
  for (int k = 0; k < 8; k++) {
    int tk = len - 1 - k;
    if (tk < 0) tk = S_ - 1;
    float g;
    if (k > tk) {
      g = NEGV;
    } else {
      const float elsv = (float)ELSb[((size_t)(b * S_ + tk)) * 512 + lane * 8 + k];
      const float ls = (elsv > 0.f) ? __logf(elsv) : NEGV;
      if (k == tk) {
        g = ls + Tfb_g[lane];
      } else if (mask[b * S_ + tk] == 1) {
        const int u = tk - 1 - k;
        const float mlin = Mg_lin[((size_t)b * S_ + u) * 64 + lane];
        const float M = (mlin > 0.f) ? (__logf(mlin) + cs_g[b * S_ + u]) : -1e30f;
        g = ls + M;
      } else {
        g = NEGV;
      }
    }
    const float v = g + t2e;
    vals[k] = v;
    mx = fmaxf(mx, v);
  }
#pragma unroll
  for (int off = 32; off > 0; off >>= 1) mx = fmaxf(mx, __shfl_xor(mx, off));
  float s = 0.f;
#pragma unroll
  for (int k = 0; k < 8; k++) s += __expf(vals[k] - mx);
#pragma unroll
  for (int off = 32; off > 0; off >>= 1) s += __shfl_xor(s, off);
  if (lane == 0) out[b] = __logf(s) + mx;
}

// ---------------------------------------------------------------------------
extern "C" void kernel_launch(void* const* d_in, const int* in_sizes, int n_in,
                              void* d_out, int out_size, void* d_ws, size_t ws_size,
                              hipStream_t stream) {
  const float* wr     = (const float*)d_in[0];
  const int*   mask   = (const int*)d_in[1];
  const float* conv_w = (const float*)d_in[2];
  const float* conv_b = (const float*)d_in[3];
  const float* cls_w  = (const float*)d_in[4];
  const float* cls_b  = (const float*)d_in[5];
  const float* T      = (const float*)d_in[6];
  const float* Tfb    = (const float*)d_in[7];
  const float* T2e    = (const float*)d_in[8];
  float* out = (float*)d_out;

  float* ws = (float*)d_ws;
  bf16_t* Vt    = (bf16_t*)ws;              // [512][4096] bf16  (1,048,576 f)
  bf16_t* Awr   = (bf16_t*)(ws + 1048576);  // [8192][512] bf16  (2,097,152 f)
  float*  bias2 = ws + 3145728;             // [8][64]
  bf16_t* ELSb  = (bf16_t*)(ws + 3146240);  // [8192][512] bf16  (2,097,152 f)
  float*  Mg    = ws + 5243392;             // [32][256][64]     (524,288 f)
  float*  cs    = ws + 5767680;             // [32][256]         (8,192 f)
  // total 5,775,872 floats = 23.1 MB

  cast_kernel<<<2048, 256, 0, stream>>>(wr, Awr);
  w2_kernel<<<dim3(8, 8, 8), 256, 0, stream>>>(conv_w, cls_w, Vt);
  bias2_kernel<<<2, 256, 0, stream>>>(conv_b, cls_w, cls_b, bias2);
  ls_mfma<<<dim3(64, 4), 256, 0, stream>>>(Awr, Vt, bias2, mask, ELSb);
  dp_kernel<<<32, 64, 0, stream>>>(T, Tfb, ELSb, Mg, cs);
  final_kernel<<<32, 64, 0, stream>>>(mask, Tfb, T2e, ELSb, Mg, cs, out);
}